// Round 16
// baseline (1790.502 us; speedup 1.0000x reference)
//
#include <hip/hip_runtime.h>
#include <hip/hip_bf16.h>

#define GB 2  // batch elems per convB block

__device__ __forceinline__ float elu1(float v) { return v > 0.f ? v : expm1f(v); }

// ---------------- cnorm: ||cb_k||^2 per code ----------------
__global__ void cnorm_kernel(const float* __restrict__ cb, float* __restrict__ cnorm) {
    int g = blockIdx.x * blockDim.x + threadIdx.x;  // 0..8191  (q*1024+k)
    if (g >= 8 * 1024) return;
    const float* p = cb + (size_t)g * 256;
    float s = 0.f;
    for (int d = 0; d < 256; d += 4) {
        float4 v = *reinterpret_cast<const float4*>(p + d);
        s += v.x * v.x + v.y * v.y + v.z * v.z + v.w * v.w;
    }
    cnorm[g] = s;
}

// ---------------- cbtrans: codebook -> stage-major layout -------------------
// cbT[(s*8 + dl)*1024 + k] = cb[((s>>5)*1024 + k)*256 + (s&31)*8 + dl]
__global__ void cbtrans_kernel(const float* __restrict__ cb, float* __restrict__ cbT) {
    int t = blockIdx.x * blockDim.x + threadIdx.x;  // 0..524287 (float4 units)
    int o = t * 4;
    const int s = o >> 13;          // stage 0..255
    const int r = o & 8191;
    const int dl = r >> 10;
    const int k = r & 1023;         // k..k+3
    const int q = s >> 5;
    const int d = (s & 31) * 8 + dl;
    const float* src = cb + ((size_t)(q * 1024 + k)) * 256 + d;
    float4 v;
    v.x = src[0 * 256]; v.y = src[1 * 256]; v.z = src[2 * 256]; v.w = src[3 * 256];
    *reinterpret_cast<float4*>(cbT + o) = v;
}

// ---------------- weight transpose to lane-major layouts (r5 strides) -------
__global__ void wtrans_kernel(const float* __restrict__ W1, const float* __restrict__ W2,
                              const float* __restrict__ W3, float* __restrict__ W1T,
                              float* __restrict__ W2T, float* __restrict__ W3T) {
    int g = blockIdx.x * blockDim.x + threadIdx.x;
    if (g < 8192) {  // W1
        int ci = g >> 7, c = g & 127;
        const float* src = W1 + c * 512 + ci * 8;
        float4 a = *reinterpret_cast<const float4*>(src);
        float4 b = *reinterpret_cast<const float4*>(src + 4);
        *reinterpret_cast<float4*>(W1T + g * 8) = a;
        *reinterpret_cast<float4*>(W1T + g * 8 + 4) = b;
    }
    int g2 = g - 8192;
    if (g2 >= 0 && g2 < 32768) {  // W2
        int ci = g2 >> 8, c = g2 & 255;
        const float* src = W2 + c * 1280 + ci * 10;
        float* dst = W2T + g2 * 10;
#pragma unroll
        for (int j = 0; j < 5; ++j)
            *reinterpret_cast<float2*>(dst + 2 * j) =
                *reinterpret_cast<const float2*>(src + 2 * j);
    }
    int g3 = g - 40960;
    if (g3 >= 0 && g3 < 65536) {  // W3 (only taps 6..11 are ever used)
        int ci = g3 >> 8, c = g3 & 255;
        const float* src = W3 + c * 3072 + ci * 12 + 6;
        float* dst = W3T + g3 * 6;
#pragma unroll
        for (int j = 0; j < 3; ++j)
            *reinterpret_cast<float2*>(dst + 2 * j) =
                *reinterpret_cast<const float2*>(src + 2 * j);
    }
}

// ================= convA v3: 2 batch/block, 2 channels/thread ================
// tid = bi*128 + half*64 + cg. Wave = constant (bi,half) -> row4 reads are
// 64-lane uniform broadcasts (free, m136). Each thread computes channels
// cg and cg+64 -> 240 FMA per 16 ds_read_b128 (2x the FMA:DS ratio of r14,
// which was DS-pipe-bound at 824us with VGPR 44).
__global__ __launch_bounds__(256, 2)
void convA_kernel(const float* __restrict__ audio,
                  const float* __restrict__ W0, const float* __restrict__ b0,
                  const float* __restrict__ W1T, const float* __restrict__ b1,
                  float* __restrict__ y1g) {
    __shared__ __align__(16) float xs[244];
    __shared__ __align__(16) float y0s[2 * 64 * 124];  // 62KB, 4 left pad cols

    const int tid = threadIdx.x;
    const int bbase = blockIdx.x * 2;

    if (tid < 128) {  // zero pad cols of both y0 tiles
        const int bz = tid >> 6, ciz = tid & 63;
        float* p = y0s + (bz * 64 + ciz) * 124;
        p[0] = 0.f; p[1] = 0.f; p[2] = 0.f; p[3] = 0.f;
    }

    for (int bi2 = 0; bi2 < 2; ++bi2) {
        __syncthreads();  // xs free (prev conv0 done reading)
        if (tid < 242) xs[tid] = (tid < 2) ? 0.f : audio[(bbase + bi2) * 240 + tid - 2];
        __syncthreads();
        // ---- conv0 (1->64, k=4, s=2) + ELU ----
        const int ci = tid >> 2, tg = tid & 3;
        float4 w = *reinterpret_cast<const float4*>(W0 + ci * 4);
        float bias = b0[ci];
        for (int t = tg; t < 120; t += 4) {
            float v = bias + w.x * xs[2 * t] + w.y * xs[2 * t + 1]
                           + w.z * xs[2 * t + 2] + w.w * xs[2 * t + 3];
            y0s[(bi2 * 64 + ci) * 124 + 4 + t] = elu1(v);
        }
    }
    __syncthreads();
    // ---- conv1 (64->128, k=8, s=4) + ELU: 2 channels per thread ----
    {
        const int bi = tid >> 7;          // 0..1
        const int half = (tid >> 6) & 1;  // 0..1
        const int cg = tid & 63;          // channel base (c0=cg, c1=cg+64)
        const int t0 = 15 * half;
        float acc0[15], acc1[15];
        const float bias0 = b1[cg], bias1 = b1[cg + 64];
#pragma unroll
        for (int u = 0; u < 15; ++u) { acc0[u] = bias0; acc1[u] = bias1; }
        const float* wbase0 = W1T + cg * 8;         // + ci*1024
        const float* ybase = y0s + bi * 64 * 124 + 4 * t0;
        for (int ci = 0; ci < 64; ++ci) {
            float4 wA0 = *reinterpret_cast<const float4*>(wbase0 + ci * 1024);
            float4 wB0 = *reinterpret_cast<const float4*>(wbase0 + ci * 1024 + 4);
            float4 wA1 = *reinterpret_cast<const float4*>(wbase0 + ci * 1024 + 512);
            float4 wB1 = *reinterpret_cast<const float4*>(wbase0 + ci * 1024 + 516);
            const float* yb = ybase + ci * 124;     // wave-uniform address
            float4 row4[16];
#pragma unroll
            for (int j = 0; j < 16; ++j)
                row4[j] = *reinterpret_cast<const float4*>(yb + 4 * j);
#pragma unroll
            for (int u = 0; u < 15; ++u) {
                acc0[u] += wA0.x * row4[u].x + wA0.y * row4[u].y
                         + wA0.z * row4[u].z + wA0.w * row4[u].w
                         + wB0.x * row4[u + 1].x + wB0.y * row4[u + 1].y
                         + wB0.z * row4[u + 1].z + wB0.w * row4[u + 1].w;
                acc1[u] += wA1.x * row4[u].x + wA1.y * row4[u].y
                         + wA1.z * row4[u].z + wA1.w * row4[u].w
                         + wB1.x * row4[u + 1].x + wB1.y * row4[u + 1].y
                         + wB1.z * row4[u + 1].z + wB1.w * row4[u + 1].w;
            }
        }
        const int b = bbase + bi;
        float* yo0 = y1g + ((size_t)b * 128 + cg) * 32 + t0;
        float* yo1 = y1g + ((size_t)b * 128 + cg + 64) * 32 + t0;
#pragma unroll
        for (int u = 0; u < 15; ++u) {
            yo0[u] = elu1(acc0[u]);
            yo1[u] = elu1(acc1[u]);
        }
    }
}

// ================= convB v3 (r12 proven): y1 direct from global ==============
__global__ __launch_bounds__(256, 2)
void convB_kernel(const float* __restrict__ state_in,
                  const float* __restrict__ b2, const float* __restrict__ b3,
                  const float* __restrict__ W2T, const float* __restrict__ W3T,
                  const float* __restrict__ y1g,
                  float* __restrict__ out, float* __restrict__ r_ws) {
    __shared__ __align__(16) float y2s[GB * 256 * 6];

    const int tid = threadIdx.x;
    const int bbase = blockIdx.x * GB;

    // ---- conv2 (128->256, k=10, s=5) + ELU ----
    {
        const int c = tid;
        float acc[GB][6];
        float bias = b2[c];
#pragma unroll
        for (int bi = 0; bi < GB; ++bi)
#pragma unroll
            for (int t = 0; t < 6; ++t) acc[bi][t] = bias;
        const float* wbase = W2T + c * 10;
        for (int ci = 0; ci < 128; ++ci) {
            float w[10];
#pragma unroll
            for (int jj = 0; jj < 5; ++jj) {
                float2 wv = *reinterpret_cast<const float2*>(wbase + ci * 2560 + jj * 2);
                w[jj * 2] = wv.x; w[jj * 2 + 1] = wv.y;
            }
#pragma unroll
            for (int bi = 0; bi < GB; ++bi) {
                const float* yr = y1g + ((size_t)(bbase + bi) * 128 + ci) * 32;
                float row[32];
#pragma unroll
                for (int k4 = 0; k4 < 8; ++k4) {
                    float4 v = *reinterpret_cast<const float4*>(yr + k4 * 4);
                    row[k4 * 4] = v.x; row[k4 * 4 + 1] = v.y;
                    row[k4 * 4 + 2] = v.z; row[k4 * 4 + 3] = v.w;
                }
                acc[bi][0] += w[5] * row[0] + w[6] * row[1] + w[7] * row[2]
                            + w[8] * row[3] + w[9] * row[4];
#pragma unroll
                for (int t = 1; t < 6; ++t) {
                    const int q0 = 5 * t - 5;
                    float s = 0.f;
#pragma unroll
                    for (int j = 0; j < 10; ++j) s += w[j] * row[q0 + j];
                    acc[bi][t] += s;
                }
            }
        }
#pragma unroll
        for (int bi = 0; bi < GB; ++bi)
#pragma unroll
            for (int t = 0; t < 6; ++t)
                y2s[(bi * 256 + c) * 6 + t] = elu1(acc[bi][t]);
    }
    __syncthreads();
    // ---- conv3 (256->256): taps 6..11 only; no ELU ----
    {
        const int c = tid;
        float acc[GB];
        float bias = b3[c];
#pragma unroll
        for (int bi = 0; bi < GB; ++bi) acc[bi] = bias;
        const float* wbase = W3T + c * 6;
        for (int ci = 0; ci < 256; ++ci) {
            float2 w01 = *reinterpret_cast<const float2*>(wbase + ci * 1536);
            float2 w23 = *reinterpret_cast<const float2*>(wbase + ci * 1536 + 2);
            float2 w45 = *reinterpret_cast<const float2*>(wbase + ci * 1536 + 4);
#pragma unroll
            for (int bi = 0; bi < GB; ++bi) {
                const float* yr = y2s + (bi * 256 + ci) * 6;
                float2 a = *reinterpret_cast<const float2*>(yr);
                float2 d = *reinterpret_cast<const float2*>(yr + 2);
                float2 e = *reinterpret_cast<const float2*>(yr + 4);
                acc[bi] += w01.x * a.x + w01.y * a.y + w23.x * d.x + w23.y * d.y
                         + w45.x * e.x + w45.y * e.y;
            }
        }
#pragma unroll
        for (int bi = 0; bi < GB; ++bi) {
            const int b = bbase + bi;
            float y3 = acc[bi];
            r_ws[b * 256 + c] = y3;
            float4 si = *reinterpret_cast<const float4*>(state_in + b * 1024 + c * 4);
            float4 o; o.x = si.y; o.y = si.z; o.z = si.w; o.w = y3;
            *reinterpret_cast<float4*>(out + 65536 + b * 1024 + c * 4) = o;
        }
    }
}

// ---------------- RVQ v6: register-direct codebook (r10 proven) --------------
__device__ __forceinline__ unsigned long long distkey(float d, int k) {
    unsigned u = __float_as_uint(d);
    u = (u & 0x80000000u) ? ~u : (u | 0x80000000u);  // monotonic float->uint
    return ((unsigned long long)u << 32) | (unsigned)k;  // low idx wins ties (np argmin)
}

__global__ __launch_bounds__(256)
void rvq_kernel(const float* __restrict__ cb, const float* __restrict__ cbT,
                const float* __restrict__ cnorm, const float* __restrict__ r_ws,
                float* __restrict__ out) {
    __shared__ __align__(16) float rs[16 * 256];  // 16 KB residuals
    __shared__ unsigned long long part_sh[2][16];
    __shared__ int idx_sh[16];

    const int tid = threadIdx.x;
    const int lane = tid & 63;
    const int wid = tid >> 6;   // 0..3
    const int bg = wid >> 1;    // 0..1: b block of 8
    const int kg = wid & 1;     // 0..1: k half of 512
    const int b0 = blockIdx.x * 16;
    const int kb = kg * 512 + 4 * lane;  // cv0 k-base (cv1 = +256)

    for (int it = 0; it < 4; ++it) {
        int o = (it * 256 + tid) * 4;
        *reinterpret_cast<float4*>(rs + o) =
            *reinterpret_cast<const float4*>(r_ws + b0 * 256 + o);
    }
    __syncthreads();

    for (int q = 0; q < 8; ++q) {
        float acc[8][8];
#pragma unroll
        for (int i = 0; i < 8; ++i)
#pragma unroll
            for (int j = 0; j < 8; ++j) acc[i][j] = 0.f;

        for (int ds = 0; ds < 32; ++ds) {
            const float* sb = cbT + (size_t)(q * 32 + ds) * 8192;
#pragma unroll
            for (int dp = 0; dp < 2; ++dp) {
                float4 cv0[4], cv1[4];
#pragma unroll
                for (int dd = 0; dd < 4; ++dd) {
                    const int dl = dp * 4 + dd;
                    cv0[dd] = *reinterpret_cast<const float4*>(sb + dl * 1024 + kb);
                    cv1[dd] = *reinterpret_cast<const float4*>(sb + dl * 1024 + kb + 256);
                }
                float rr[8][4];
#pragma unroll
                for (int i = 0; i < 8; ++i) {
                    float4 t = *reinterpret_cast<const float4*>(
                        rs + (bg * 8 + i) * 256 + ds * 8 + dp * 4);
                    rr[i][0] = t.x; rr[i][1] = t.y; rr[i][2] = t.z; rr[i][3] = t.w;
                }
#pragma unroll
                for (int dd = 0; dd < 4; ++dd) {
#pragma unroll
                    for (int i = 0; i < 8; ++i) {
                        const float r = rr[i][dd];
                        acc[i][0] += r * cv0[dd].x; acc[i][1] += r * cv0[dd].y;
                        acc[i][2] += r * cv0[dd].z; acc[i][3] += r * cv0[dd].w;
                        acc[i][4] += r * cv1[dd].x; acc[i][5] += r * cv1[dd].y;
                        acc[i][6] += r * cv1[dd].z; acc[i][7] += r * cv1[dd].w;
                    }
                }
            }
        }
        {
            float4 cn0 = *reinterpret_cast<const float4*>(cnorm + q * 1024 + kb);
            float4 cn1 = *reinterpret_cast<const float4*>(cnorm + q * 1024 + kb + 256);
            float c0e[4] = {cn0.x, cn0.y, cn0.z, cn0.w};
            float c1e[4] = {cn1.x, cn1.y, cn1.z, cn1.w};
#pragma unroll
            for (int i = 0; i < 8; ++i) {
                unsigned long long k = 0xFFFFFFFFFFFFFFFFull;
#pragma unroll
                for (int e = 0; e < 4; ++e) {
                    unsigned long long ka = distkey(c0e[e] - 2.f * acc[i][e], kb + e);
                    unsigned long long kc = distkey(c1e[e] - 2.f * acc[i][4 + e],
                                                    kb + 256 + e);
                    if (ka < k) k = ka;
                    if (kc < k) k = kc;
                }
                for (int off = 32; off >= 1; off >>= 1) {
                    unsigned long long o = __shfl_xor(k, off, 64);
                    if (o < k) k = o;
                }
                if (lane == 0) part_sh[kg][bg * 8 + i] = k;
            }
        }
        __syncthreads();
        if (tid < 16) {
            unsigned long long ka = part_sh[0][tid];
            unsigned long long kc = part_sh[1][tid];
            if (kc < ka) ka = kc;
            const int idx = (int)(ka & 0xFFFFFFFFu);
            idx_sh[tid] = idx;
            out[(b0 + tid) * 8 + q] = (float)idx;
        }
        __syncthreads();
        for (int it = 0; it < 16; ++it) {
            const int idx = idx_sh[it];
            rs[it * 256 + tid] -= cb[((size_t)(q * 1024 + idx)) * 256 + tid];
        }
        __syncthreads();
    }
}

extern "C" void kernel_launch(void* const* d_in, const int* in_sizes, int n_in,
                              void* d_out, int out_size, void* d_ws, size_t ws_size,
                              hipStream_t stream) {
    const float* audio = (const float*)d_in[0];
    const float* state = (const float*)d_in[1];
    const float* W0 = (const float*)d_in[2];
    const float* b0 = (const float*)d_in[3];
    const float* W1 = (const float*)d_in[4];
    const float* b1 = (const float*)d_in[5];
    const float* W2 = (const float*)d_in[6];
    const float* b2 = (const float*)d_in[7];
    const float* W3 = (const float*)d_in[8];
    const float* b3 = (const float*)d_in[9];
    const float* cbk = (const float*)d_in[10];
    float* out = (float*)d_out;

    float* cnorm_ws = (float*)d_ws;            // 8192
    float* r_ws = cnorm_ws + 8192;             // 2097152
    float* W1T = r_ws + 2097152;               // 65536
    float* W2T = W1T + 65536;                  // 327680 (stride 10)
    float* W3T = W2T + 327680;                 // 393216 (stride 6)
    float* y1g = W3T + 393216;                 // 33554432
    float* cbT = y1g + 33554432;               // 2097152 (8MB staged codebook)
    // total ~154 MB; ws>=196MB proven in r7

    cnorm_kernel<<<32, 256, 0, stream>>>(cbk, cnorm_ws);
    cbtrans_kernel<<<2048, 256, 0, stream>>>(cbk, cbT);
    wtrans_kernel<<<416, 256, 0, stream>>>(W1, W2, W3, W1T, W2T, W3T);
    convA_kernel<<<4096, 256, 0, stream>>>(audio, W0, b0, W1T, b1, y1g);
    convB_kernel<<<8192 / GB, 256, 0, stream>>>(state, b2, b3, W2T, W3T, y1g,
                                                out, r_ws);
    rvq_kernel<<<512, 256, 0, stream>>>(cbk, cbT, cnorm_ws, r_ws, out);
}

// Round 17
// 1771.731 us; speedup vs baseline: 1.0106x; 1.0106x over previous
//
#include <hip/hip_runtime.h>
#include <hip/hip_bf16.h>

#define GB 2  // batch elems per convB block

__device__ __forceinline__ float elu1(float v) { return v > 0.f ? v : expm1f(v); }

// ---------------- cnorm: ||cb_k||^2 per code ----------------
__global__ void cnorm_kernel(const float* __restrict__ cb, float* __restrict__ cnorm) {
    int g = blockIdx.x * blockDim.x + threadIdx.x;  // 0..8191  (q*1024+k)
    if (g >= 8 * 1024) return;
    const float* p = cb + (size_t)g * 256;
    float s = 0.f;
    for (int d = 0; d < 256; d += 4) {
        float4 v = *reinterpret_cast<const float4*>(p + d);
        s += v.x * v.x + v.y * v.y + v.z * v.z + v.w * v.w;
    }
    cnorm[g] = s;
}

// ---------------- cbtrans: codebook -> stage-major layout -------------------
__global__ void cbtrans_kernel(const float* __restrict__ cb, float* __restrict__ cbT) {
    int t = blockIdx.x * blockDim.x + threadIdx.x;  // 0..524287 (float4 units)
    int o = t * 4;
    const int s = o >> 13;
    const int r = o & 8191;
    const int dl = r >> 10;
    const int k = r & 1023;
    const int q = s >> 5;
    const int d = (s & 31) * 8 + dl;
    const float* src = cb + ((size_t)(q * 1024 + k)) * 256 + d;
    float4 v;
    v.x = src[0 * 256]; v.y = src[1 * 256]; v.z = src[2 * 256]; v.w = src[3 * 256];
    *reinterpret_cast<float4*>(cbT + o) = v;
}

// ------------- wtrans v2: LANE-DENSE transposed weight layouts --------------
// W1c[((ci*4+io)*64+cg)*4]: io0=wA(cg) io1=wB(cg) io2=wA(cg+64) io3=wB(cg+64)
// W2c[((ci*3+jq)*256+c)*4]: j = 4*jq+e (j>=10 -> 0)
// W3c[((ci*3+jq)*256+c)*2]: taps 6+2*jq, 7+2*jq
__global__ void wtrans_kernel(const float* __restrict__ W1, const float* __restrict__ W2,
                              const float* __restrict__ W3, float* __restrict__ W1c,
                              float* __restrict__ W2c, float* __restrict__ W3c) {
    int g = blockIdx.x * blockDim.x + threadIdx.x;
    if (g < 16384) {  // W1c, float4 units
        int ci = g >> 8, io = (g >> 6) & 3, cg = g & 63;
        int c = cg + (io >> 1) * 64;
        const float* src = W1 + c * 512 + ci * 8 + (io & 1) * 4;
        *reinterpret_cast<float4*>(W1c + g * 4) =
            *reinterpret_cast<const float4*>(src);
    }
    int g2 = g - 16384;
    if (g2 >= 0 && g2 < 98304) {  // W2c, float4 units
        int ci = g2 / 768, rem = g2 % 768;
        int jq = rem >> 8, c = rem & 255;
        float v[4];
#pragma unroll
        for (int e = 0; e < 4; ++e) {
            int j = jq * 4 + e;
            v[e] = (j < 10) ? W2[c * 1280 + ci * 10 + j] : 0.f;
        }
        float4 o; o.x = v[0]; o.y = v[1]; o.z = v[2]; o.w = v[3];
        *reinterpret_cast<float4*>(W2c + g2 * 4) = o;
    }
    int g3 = g - 16384 - 98304;
    if (g3 >= 0 && g3 < 196608) {  // W3c, float2 units
        int ci = g3 / 768, rem = g3 % 768;
        int jq = rem >> 8, c = rem & 255;
        const float* src = W3 + c * 3072 + ci * 12 + 6 + jq * 2;
        W3c[g3 * 2] = src[0];
        W3c[g3 * 2 + 1] = src[1];
    }
}

// ================= convA v3 (r16 body) + lane-dense W1c loads ================
__global__ __launch_bounds__(256, 2)
void convA_kernel(const float* __restrict__ audio,
                  const float* __restrict__ W0, const float* __restrict__ b0,
                  const float* __restrict__ W1c, const float* __restrict__ b1,
                  float* __restrict__ y1g) {
    __shared__ __align__(16) float xs[244];
    __shared__ __align__(16) float y0s[2 * 64 * 124];  // 62KB, 4 left pad cols

    const int tid = threadIdx.x;
    const int bbase = blockIdx.x * 2;

    if (tid < 128) {  // zero pad cols of both y0 tiles
        const int bz = tid >> 6, ciz = tid & 63;
        float* p = y0s + (bz * 64 + ciz) * 124;
        p[0] = 0.f; p[1] = 0.f; p[2] = 0.f; p[3] = 0.f;
    }

    for (int bi2 = 0; bi2 < 2; ++bi2) {
        __syncthreads();
        if (tid < 242) xs[tid] = (tid < 2) ? 0.f : audio[(bbase + bi2) * 240 + tid - 2];
        __syncthreads();
        const int ci = tid >> 2, tg = tid & 3;
        float4 w = *reinterpret_cast<const float4*>(W0 + ci * 4);
        float bias = b0[ci];
        for (int t = tg; t < 120; t += 4) {
            float v = bias + w.x * xs[2 * t] + w.y * xs[2 * t + 1]
                           + w.z * xs[2 * t + 2] + w.w * xs[2 * t + 3];
            y0s[(bi2 * 64 + ci) * 124 + 4 + t] = elu1(v);
        }
    }
    __syncthreads();
    // ---- conv1 (64->128, k=8, s=4) + ELU: 2 channels per thread ----
    {
        const int bi = tid >> 7;
        const int half = (tid >> 6) & 1;
        const int cg = tid & 63;
        const int t0 = 15 * half;
        float acc0[15], acc1[15];
        const float bias0 = b1[cg], bias1 = b1[cg + 64];
#pragma unroll
        for (int u = 0; u < 15; ++u) { acc0[u] = bias0; acc1[u] = bias1; }
        const float* w1base = W1c + cg * 4;   // + (ci*4+io)*256
        const float* ybase = y0s + bi * 64 * 124 + 4 * t0;
        for (int ci = 0; ci < 64; ++ci) {
            float4 wA0 = *reinterpret_cast<const float4*>(w1base + (ci * 4 + 0) * 256);
            float4 wB0 = *reinterpret_cast<const float4*>(w1base + (ci * 4 + 1) * 256);
            float4 wA1 = *reinterpret_cast<const float4*>(w1base + (ci * 4 + 2) * 256);
            float4 wB1 = *reinterpret_cast<const float4*>(w1base + (ci * 4 + 3) * 256);
            const float* yb = ybase + ci * 124;     // wave-uniform address
            float4 row4[16];
#pragma unroll
            for (int j = 0; j < 16; ++j)
                row4[j] = *reinterpret_cast<const float4*>(yb + 4 * j);
#pragma unroll
            for (int u = 0; u < 15; ++u) {
                acc0[u] += wA0.x * row4[u].x + wA0.y * row4[u].y
                         + wA0.z * row4[u].z + wA0.w * row4[u].w
                         + wB0.x * row4[u + 1].x + wB0.y * row4[u + 1].y
                         + wB0.z * row4[u + 1].z + wB0.w * row4[u + 1].w;
                acc1[u] += wA1.x * row4[u].x + wA1.y * row4[u].y
                         + wA1.z * row4[u].z + wA1.w * row4[u].w
                         + wB1.x * row4[u + 1].x + wB1.y * row4[u + 1].y
                         + wB1.z * row4[u + 1].z + wB1.w * row4[u + 1].w;
            }
        }
        const int b = bbase + bi;
        float* yo0 = y1g + ((size_t)b * 128 + cg) * 32 + t0;
        float* yo1 = y1g + ((size_t)b * 128 + cg + 64) * 32 + t0;
#pragma unroll
        for (int u = 0; u < 15; ++u) {
            yo0[u] = elu1(acc0[u]);
            yo1[u] = elu1(acc1[u]);
        }
    }
}

// ================= convB v4: r12 body + lane-dense W2c/W3c loads =============
__global__ __launch_bounds__(256, 2)
void convB_kernel(const float* __restrict__ state_in,
                  const float* __restrict__ b2, const float* __restrict__ b3,
                  const float* __restrict__ W2c, const float* __restrict__ W3c,
                  const float* __restrict__ y1g,
                  float* __restrict__ out, float* __restrict__ r_ws) {
    __shared__ __align__(16) float y2s[GB * 256 * 6];

    const int tid = threadIdx.x;
    const int bbase = blockIdx.x * GB;

    // ---- conv2 (128->256, k=10, s=5) + ELU ----
    {
        const int c = tid;
        float acc[GB][6];
        float bias = b2[c];
#pragma unroll
        for (int bi = 0; bi < GB; ++bi)
#pragma unroll
            for (int t = 0; t < 6; ++t) acc[bi][t] = bias;
        const float* w2base = W2c + c * 4;  // + (ci*3+jq)*1024
        for (int ci = 0; ci < 128; ++ci) {
            float4 a0 = *reinterpret_cast<const float4*>(w2base + (ci * 3 + 0) * 1024);
            float4 a1 = *reinterpret_cast<const float4*>(w2base + (ci * 3 + 1) * 1024);
            float4 a2 = *reinterpret_cast<const float4*>(w2base + (ci * 3 + 2) * 1024);
            const float w[10] = {a0.x, a0.y, a0.z, a0.w, a1.x,
                                 a1.y, a1.z, a1.w, a2.x, a2.y};
#pragma unroll
            for (int bi = 0; bi < GB; ++bi) {
                const float* yr = y1g + ((size_t)(bbase + bi) * 128 + ci) * 32;
                float row[32];
#pragma unroll
                for (int k4 = 0; k4 < 8; ++k4) {
                    float4 v = *reinterpret_cast<const float4*>(yr + k4 * 4);
                    row[k4 * 4] = v.x; row[k4 * 4 + 1] = v.y;
                    row[k4 * 4 + 2] = v.z; row[k4 * 4 + 3] = v.w;
                }
                acc[bi][0] += w[5] * row[0] + w[6] * row[1] + w[7] * row[2]
                            + w[8] * row[3] + w[9] * row[4];
#pragma unroll
                for (int t = 1; t < 6; ++t) {
                    const int q0 = 5 * t - 5;
                    float s = 0.f;
#pragma unroll
                    for (int j = 0; j < 10; ++j) s += w[j] * row[q0 + j];
                    acc[bi][t] += s;
                }
            }
        }
#pragma unroll
        for (int bi = 0; bi < GB; ++bi)
#pragma unroll
            for (int t = 0; t < 6; ++t)
                y2s[(bi * 256 + c) * 6 + t] = elu1(acc[bi][t]);
    }
    __syncthreads();
    // ---- conv3 (256->256): taps 6..11 only; no ELU ----
    {
        const int c = tid;
        float acc[GB];
        float bias = b3[c];
#pragma unroll
        for (int bi = 0; bi < GB; ++bi) acc[bi] = bias;
        const float* w3base = W3c + c * 2;  // + (ci*3+jq)*512
        for (int ci = 0; ci < 256; ++ci) {
            float2 w01 = *reinterpret_cast<const float2*>(w3base + (ci * 3 + 0) * 512);
            float2 w23 = *reinterpret_cast<const float2*>(w3base + (ci * 3 + 1) * 512);
            float2 w45 = *reinterpret_cast<const float2*>(w3base + (ci * 3 + 2) * 512);
#pragma unroll
            for (int bi = 0; bi < GB; ++bi) {
                const float* yr = y2s + (bi * 256 + ci) * 6;
                float2 a = *reinterpret_cast<const float2*>(yr);
                float2 d = *reinterpret_cast<const float2*>(yr + 2);
                float2 e = *reinterpret_cast<const float2*>(yr + 4);
                acc[bi] += w01.x * a.x + w01.y * a.y + w23.x * d.x + w23.y * d.y
                         + w45.x * e.x + w45.y * e.y;
            }
        }
#pragma unroll
        for (int bi = 0; bi < GB; ++bi) {
            const int b = bbase + bi;
            float y3 = acc[bi];
            r_ws[b * 256 + c] = y3;
            float4 si = *reinterpret_cast<const float4*>(state_in + b * 1024 + c * 4);
            float4 o; o.x = si.y; o.y = si.z; o.z = si.w; o.w = y3;
            *reinterpret_cast<float4*>(out + 65536 + b * 1024 + c * 4) = o;
        }
    }
}

// ---------------- RVQ v6: register-direct codebook (r10 proven) --------------
__device__ __forceinline__ unsigned long long distkey(float d, int k) {
    unsigned u = __float_as_uint(d);
    u = (u & 0x80000000u) ? ~u : (u | 0x80000000u);  // monotonic float->uint
    return ((unsigned long long)u << 32) | (unsigned)k;  // low idx wins ties (np argmin)
}

__global__ __launch_bounds__(256)
void rvq_kernel(const float* __restrict__ cb, const float* __restrict__ cbT,
                const float* __restrict__ cnorm, const float* __restrict__ r_ws,
                float* __restrict__ out) {
    __shared__ __align__(16) float rs[16 * 256];  // 16 KB residuals
    __shared__ unsigned long long part_sh[2][16];
    __shared__ int idx_sh[16];

    const int tid = threadIdx.x;
    const int lane = tid & 63;
    const int wid = tid >> 6;
    const int bg = wid >> 1;
    const int kg = wid & 1;
    const int b0 = blockIdx.x * 16;
    const int kb = kg * 512 + 4 * lane;

    for (int it = 0; it < 4; ++it) {
        int o = (it * 256 + tid) * 4;
        *reinterpret_cast<float4*>(rs + o) =
            *reinterpret_cast<const float4*>(r_ws + b0 * 256 + o);
    }
    __syncthreads();

    for (int q = 0; q < 8; ++q) {
        float acc[8][8];
#pragma unroll
        for (int i = 0; i < 8; ++i)
#pragma unroll
            for (int j = 0; j < 8; ++j) acc[i][j] = 0.f;

        for (int ds = 0; ds < 32; ++ds) {
            const float* sb = cbT + (size_t)(q * 32 + ds) * 8192;
#pragma unroll
            for (int dp = 0; dp < 2; ++dp) {
                float4 cv0[4], cv1[4];
#pragma unroll
                for (int dd = 0; dd < 4; ++dd) {
                    const int dl = dp * 4 + dd;
                    cv0[dd] = *reinterpret_cast<const float4*>(sb + dl * 1024 + kb);
                    cv1[dd] = *reinterpret_cast<const float4*>(sb + dl * 1024 + kb + 256);
                }
                float rr[8][4];
#pragma unroll
                for (int i = 0; i < 8; ++i) {
                    float4 t = *reinterpret_cast<const float4*>(
                        rs + (bg * 8 + i) * 256 + ds * 8 + dp * 4);
                    rr[i][0] = t.x; rr[i][1] = t.y; rr[i][2] = t.z; rr[i][3] = t.w;
                }
#pragma unroll
                for (int dd = 0; dd < 4; ++dd) {
#pragma unroll
                    for (int i = 0; i < 8; ++i) {
                        const float r = rr[i][dd];
                        acc[i][0] += r * cv0[dd].x; acc[i][1] += r * cv0[dd].y;
                        acc[i][2] += r * cv0[dd].z; acc[i][3] += r * cv0[dd].w;
                        acc[i][4] += r * cv1[dd].x; acc[i][5] += r * cv1[dd].y;
                        acc[i][6] += r * cv1[dd].z; acc[i][7] += r * cv1[dd].w;
                    }
                }
            }
        }
        {
            float4 cn0 = *reinterpret_cast<const float4*>(cnorm + q * 1024 + kb);
            float4 cn1 = *reinterpret_cast<const float4*>(cnorm + q * 1024 + kb + 256);
            float c0e[4] = {cn0.x, cn0.y, cn0.z, cn0.w};
            float c1e[4] = {cn1.x, cn1.y, cn1.z, cn1.w};
#pragma unroll
            for (int i = 0; i < 8; ++i) {
                unsigned long long k = 0xFFFFFFFFFFFFFFFFull;
#pragma unroll
                for (int e = 0; e < 4; ++e) {
                    unsigned long long ka = distkey(c0e[e] - 2.f * acc[i][e], kb + e);
                    unsigned long long kc = distkey(c1e[e] - 2.f * acc[i][4 + e],
                                                    kb + 256 + e);
                    if (ka < k) k = ka;
                    if (kc < k) k = kc;
                }
                for (int off = 32; off >= 1; off >>= 1) {
                    unsigned long long o = __shfl_xor(k, off, 64);
                    if (o < k) k = o;
                }
                if (lane == 0) part_sh[kg][bg * 8 + i] = k;
            }
        }
        __syncthreads();
        if (tid < 16) {
            unsigned long long ka = part_sh[0][tid];
            unsigned long long kc = part_sh[1][tid];
            if (kc < ka) ka = kc;
            const int idx = (int)(ka & 0xFFFFFFFFu);
            idx_sh[tid] = idx;
            out[(b0 + tid) * 8 + q] = (float)idx;
        }
        __syncthreads();
        for (int it = 0; it < 16; ++it) {
            const int idx = idx_sh[it];
            rs[it * 256 + tid] -= cb[((size_t)(q * 1024 + idx)) * 256 + tid];
        }
        __syncthreads();
    }
}

extern "C" void kernel_launch(void* const* d_in, const int* in_sizes, int n_in,
                              void* d_out, int out_size, void* d_ws, size_t ws_size,
                              hipStream_t stream) {
    const float* audio = (const float*)d_in[0];
    const float* state = (const float*)d_in[1];
    const float* W0 = (const float*)d_in[2];
    const float* b0 = (const float*)d_in[3];
    const float* W1 = (const float*)d_in[4];
    const float* b1 = (const float*)d_in[5];
    const float* W2 = (const float*)d_in[6];
    const float* b2 = (const float*)d_in[7];
    const float* W3 = (const float*)d_in[8];
    const float* b3 = (const float*)d_in[9];
    const float* cbk = (const float*)d_in[10];
    float* out = (float*)d_out;

    float* cnorm_ws = (float*)d_ws;            // 8192
    float* r_ws = cnorm_ws + 8192;             // 2097152
    float* W1c = r_ws + 2097152;               // 65536
    float* W2c = W1c + 65536;                  // 393216
    float* W3c = W2c + 393216;                 // 393216
    float* y1g = W3c + 393216;                 // 33554432
    float* cbT = y1g + 33554432;               // 2097152
    // total ~154 MB; ws>=196MB proven in r7

    cnorm_kernel<<<32, 256, 0, stream>>>(cbk, cnorm_ws);
    cbtrans_kernel<<<2048, 256, 0, stream>>>(cbk, cbT);
    wtrans_kernel<<<1216, 256, 0, stream>>>(W1, W2, W3, W1c, W2c, W3c);
    convA_kernel<<<4096, 256, 0, stream>>>(audio, W0, b0, W1c, b1, y1g);
    convB_kernel<<<8192 / GB, 256, 0, stream>>>(state, b2, b3, W2c, W3c, y1g,
                                                out, r_ws);
    rvq_kernel<<<512, 256, 0, stream>>>(cbk, cbT, cnorm_ws, r_ws, out);
}